// Round 17
// baseline (15.784 us; speedup 1.0000x reference)
//
#include <hip/hip_runtime.h>

typedef __attribute__((ext_vector_type(8)))  short bf16x8;
typedef __attribute__((ext_vector_type(16))) float f32x16;

#define NPART   2048
#define NCOMP   8192
#define NBATCH  8
#define THRESH  0.05f
#define FLTMAX  3.4028235e38f

#define WAVES   16
#define PTSBLK  256
#define PTILES  (PTSBLK / 32)              // 8 point-tiles (B cols) per block
#define ACHUNKS 4                          // A-chunks per wave = 4 x 32 = 128 partials
#define BLKSPB  (NCOMP / PTSBLK)           // 32 blocks per batch
#define GRID    (NBATCH * BLKSPB)          // 256 blocks

__device__ __forceinline__ unsigned int bf16rne(float x) {
    unsigned int b = __float_as_uint(x);
    return (b + 0x7FFFu + ((b >> 16) & 1u)) >> 16;
}
__device__ __forceinline__ float bf16tof(unsigned int h) {
    return __uint_as_float(h << 16);
}

union frag_cast { uint4 u; bf16x8 v; };

// Split-precision bf16 encoding on 32x32x16 (verified absmax=0 in R15):
//   A row (partial) k0..15 = [qhx,qhy,qhz, qhx,qhy,qhz, qlx,qly | qlz, p2h, p2l, 0...]
//   B col (point)   k0..15 = [chx,chy,chz, clx,cly,clz, chx,chy | chz, 1, 1, 0...]
//   dot = qh.ch + qh.cl + ql.ch + p2  ~=  -2 c.p + |p|^2   (err ~3e-5)
// Lane maps: A row = l&31, B col = l&31, k-half = l>>5.
// D: col = l&31; 16 regs x 2 lane-halves bijective over 32 partial-rows ->
// min-fold is row-mapping-agnostic.
// NOTE (R16 lesson): do NOT consume MFMA results with inline-asm VALU --
// the MFMA->VALU wait-state insertion mishandles opaque asm consumers and
// yields sporadically-stale accumulator reads. Pure fminf only; nested
// fminf(fminf(a,b),c) is the clang-fusable v_min3 shape (T17).
__global__ __launch_bounds__(1024, 4) void pml_main(
    const float* __restrict__ completed,
    const float* __restrict__ partial,
    float2* __restrict__ slots_out)
{
    const int tid  = threadIdx.x;
    const int lane = tid & 63;
    const int wave = tid >> 6;            // 0..15, owns 128 partials
    const int g    = lane >> 5;           // k-half
    const int lc   = lane & 31;           // A row (partial) / B col (point)
    const int batch = blockIdx.x >> 5;
    const int blkb  = blockIdx.x & (BLKSPB - 1);

    __shared__ uint4 sB[PTILES][2][32];         // 8 KB B-frags (points)
    __shared__ float smin[PTSBLK][WAVES + 1];   // 17 KB, pitch 17
    __shared__ float        rs[4];
    __shared__ unsigned int rc[4];

    const size_t cbase = ((size_t)batch * NCOMP + (size_t)blkb * PTSBLK) * 3;

    // ---- encode B-frags (block's 256 points) into LDS: tid<512 ----
    if (tid < 512) {
        const int tt = tid >> 6;              // tile 0..7
        const int idx = tid & 63;
        const int bg = idx >> 5;              // k-half 0/1
        const int pt = idx & 31;              // point col in tile
        const float* p = completed + cbase + 3 * (tt * 32 + pt);
        float x = p[0], y = p[1], z = p[2];
        uint4 o;
        if (bg == 0) {                        // k0..7
            unsigned int hx = bf16rne(x), hy = bf16rne(y), hz = bf16rne(z);
            unsigned int lx = bf16rne(x - bf16tof(hx));
            unsigned int ly = bf16rne(y - bf16tof(hy));
            unsigned int lz = bf16rne(z - bf16tof(hz));
            o.x = hx | (hy << 16);
            o.y = hz | (lx << 16);
            o.z = ly | (lz << 16);
            o.w = hx | (hy << 16);
        } else {                              // k8..15 = [chz, 1, 1, 0...]
            unsigned int hz = bf16rne(z);
            o.x = hz | (0x3F80u << 16);
            o.y = 0x3F80u;
            o.z = 0u;
            o.w = 0u;
        }
        sB[tt][bg][pt] = o;
    }

    // ---- encode this wave's 4 A-chunks (128 partials) in-register ----
    bf16x8 pa[ACHUNKS];
    {
        const size_t pbase = (size_t)batch * NPART + (size_t)wave * 128;
        #pragma unroll
        for (int i = 0; i < ACHUNKS; ++i) {
            const float* pp = partial + 3 * (pbase + i * 32 + lc);
            float px = pp[0], py = pp[1], pz = pp[2];
            frag_cast fc; fc.u = make_uint4(0u, 0u, 0u, 0u);
            if (g == 0) {                     // k0..7
                float qx = -2.0f * px, qy = -2.0f * py, qz = -2.0f * pz;
                unsigned int qhx = bf16rne(qx), qhy = bf16rne(qy), qhz = bf16rne(qz);
                unsigned int qlx = bf16rne(qx - bf16tof(qhx));
                unsigned int qly = bf16rne(qy - bf16tof(qhy));
                fc.u.x = qhx | (qhy << 16);
                fc.u.y = qhz | (qhx << 16);
                fc.u.z = qhy | (qhz << 16);
                fc.u.w = qlx | (qly << 16);
            } else {                          // k8..15 = [qlz, p2h, p2l, 0...]
                float qz = -2.0f * pz;
                float p2 = fmaf(px, px, fmaf(py, py, pz * pz));
                unsigned int qhz = bf16rne(qz);
                unsigned int qlz = bf16rne(qz - bf16tof(qhz));
                unsigned int p2h = bf16rne(p2);
                unsigned int p2l = bf16rne(p2 - bf16tof(p2h));
                fc.u.x = qlz | (p2h << 16);
                fc.u.y = p2l;
            }
            pa[i] = fc.v;
        }
    }

    __syncthreads();   // sB visible

    const f32x16 zero16 = {0.0f, 0.0f, 0.0f, 0.0f, 0.0f, 0.0f, 0.0f, 0.0f,
                           0.0f, 0.0f, 0.0f, 0.0f, 0.0f, 0.0f, 0.0f, 0.0f};

    // ---- sweep 8 point-tiles: 4 independent MFMAs, then balanced fmin tree ----
    for (int tile = 0; tile < PTILES; ++tile) {
        frag_cast fc; fc.u = sB[tile][g][lc];
        bf16x8 bf = fc.v;

        f32x16 d0 = __builtin_amdgcn_mfma_f32_32x32x16_bf16(pa[0], bf, zero16, 0, 0, 0);
        f32x16 d1 = __builtin_amdgcn_mfma_f32_32x32x16_bf16(pa[1], bf, zero16, 0, 0, 0);
        f32x16 d2 = __builtin_amdgcn_mfma_f32_32x32x16_bf16(pa[2], bf, zero16, 0, 0, 0);
        f32x16 d3 = __builtin_amdgcn_mfma_f32_32x32x16_bf16(pa[3], bf, zero16, 0, 0, 0);

        // 64 -> 16 -> 1: 63 fmin, depth 6, fusable (fmin(fmin(a,b),c)) shapes
        float n[16];
        #pragma unroll
        for (int q = 0; q < 16; ++q)
            n[q] = fminf(fminf(d0[q], d1[q]), fminf(d2[q], d3[q]));
        float p4[8];
        #pragma unroll
        for (int j = 0; j < 8; ++j) p4[j] = fminf(n[2 * j], n[2 * j + 1]);
        float p2r[4];
        #pragma unroll
        for (int j = 0; j < 4; ++j) p2r[j] = fminf(p4[2 * j], p4[2 * j + 1]);
        float m = fminf(fminf(p2r[0], p2r[1]), fminf(p2r[2], p2r[3]));

        m = fminf(m, __int_as_float(__shfl_xor(__float_as_int(m), 32, 64)));
        if (lane < 32)
            smin[tile * 32 + lc][wave] = m;   // banks (17*(t*32+l))%32: bijective
    }
    __syncthreads();

    // ---- combine 16 wave-minima per point (tree), +c2, mask, reduce ----
    float        v = 0.0f;
    unsigned int c = 0u;
    if (tid < PTSBLK) {
        const float* sm = smin[tid];
        float a0 = fminf(sm[0],  sm[1]);
        float a1 = fminf(sm[2],  sm[3]);
        float a2 = fminf(sm[4],  sm[5]);
        float a3 = fminf(sm[6],  sm[7]);
        float a4 = fminf(sm[8],  sm[9]);
        float a5 = fminf(sm[10], sm[11]);
        float a6 = fminf(sm[12], sm[13]);
        float a7 = fminf(sm[14], sm[15]);
        float b0 = fminf(fminf(a0, a1), fminf(a2, a3));
        float b1 = fminf(fminf(a4, a5), fminf(a6, a7));
        float t  = fminf(b0, b1);
        const float* cp = completed + cbase + 3 * tid;
        float x = cp[0], y = cp[1], z = cp[2];
        float c2 = fmaf(x, x, fmaf(y, y, z * z));
        float m = fmaxf(c2 + t, 0.0f);
        if (m < THRESH) { v = m; c = 1u; }
        #pragma unroll
        for (int off = 32; off >= 1; off >>= 1) {
            v += __shfl_down(v, off, 64);
            c += __shfl_down(c, off, 64);
        }
        if ((tid & 63) == 0) { rs[tid >> 6] = v; rc[tid >> 6] = c; }
    }
    __syncthreads();
    if (tid == 0) {
        float        bs = 0.0f;
        unsigned int bc = 0u;
        #pragma unroll
        for (int w = 0; w < PTSBLK / 64; ++w) { bs += rs[w]; bc += rc[w]; }
        slots_out[blockIdx.x] = make_float2(bs, (float)bc);
    }
}

__global__ __launch_bounds__(256) void pml_fin(
    const float2* __restrict__ slots_in,
    float* __restrict__ out)
{
    const int tid = threadIdx.x;
    float2 sl = slots_in[tid];               // GRID == 256 == blockDim
    float s = sl.x, c = sl.y;
    #pragma unroll
    for (int off = 32; off >= 1; off >>= 1) {
        s += __shfl_down(s, off, 64);
        c += __shfl_down(c, off, 64);
    }
    __shared__ float ss[4], sc[4];
    if ((tid & 63) == 0) { ss[tid >> 6] = s; sc[tid >> 6] = c; }
    __syncthreads();
    if (tid == 0) {
        float s2 = ss[0] + ss[1] + ss[2] + ss[3];
        float c2 = sc[0] + sc[1] + sc[2] + sc[3];
        *out = (c2 > 0.0f) ? (s2 / (c2 + 1e-6f)) : 0.0f;   // WEIGHT = 1.0
    }
}

extern "C" void kernel_launch(void* const* d_in, const int* in_sizes, int n_in,
                              void* d_out, int out_size, void* d_ws, size_t ws_size,
                              hipStream_t stream) {
    const float* completed = (const float*)d_in[0];  // (8, 8192, 3) f32
    const float* partial   = (const float*)d_in[1];  // (8, 2048, 3) f32
    float* out = (float*)d_out;
    float2* slots = (float2*)d_ws;                   // 256 slots, all written
                                                     // before fin reads them:
                                                     // no memset node needed

    pml_main<<<dim3(GRID), dim3(1024), 0, stream>>>(completed, partial, slots);
    pml_fin<<<dim3(1), dim3(256), 0, stream>>>(slots, out);
}

// Round 18
// 14.165 us; speedup vs baseline: 1.1143x; 1.1143x over previous
//
#include <hip/hip_runtime.h>

typedef __attribute__((ext_vector_type(8)))  short bf16x8;
typedef __attribute__((ext_vector_type(16))) float f32x16;

#define NPART   2048
#define NCOMP   8192
#define NBATCH  8
#define THRESH  0.05f
#define FLTMAX  3.4028235e38f

#define WAVES   16
#define PTSBLK  256
#define PTILES  (PTSBLK / 32)              // 8 point-tiles (B cols) per block
#define ACHUNKS 4                          // A-chunks per wave = 4 x 32 = 128 partials
#define BLKSPB  (NCOMP / PTSBLK)           // 32 blocks per batch
#define GRID    (NBATCH * BLKSPB)          // 256 blocks

__device__ __forceinline__ unsigned int bf16rne(float x) {
    unsigned int b = __float_as_uint(x);
    return (b + 0x7FFFu + ((b >> 16) & 1u)) >> 16;
}
__device__ __forceinline__ float bf16tof(unsigned int h) {
    return __uint_as_float(h << 16);
}

union frag_cast { uint4 u; bf16x8 v; };

// Split-precision bf16 encoding on 32x32x16 (verified absmax=0 in R15):
//   A row (partial) k0..15 = [qhx,qhy,qhz, qhx,qhy,qhz, qlx,qly | qlz, p2h, p2l, 0...]
//   B col (point)   k0..15 = [chx,chy,chz, clx,cly,clz, chx,chy | chz, 1, 1, 0...]
//   dot = qh.ch + qh.cl + ql.ch + p2  ~=  -2 c.p + |p|^2   (err ~3e-5)
// Lane maps: A row = l&31, B col = l&31, k-half = l>>5.
// D: col = l&31; 16 regs x 2 lane-halves bijective over 32 partial-rows ->
// the min-fold is row-mapping-agnostic.
// R16 lesson: never consume MFMA results with inline-asm VALU (hazard
// wait-states mishandled for opaque asm). R17 lesson: serial accumulate
// (32 live regs) pipelines better than 4-live-MFMA tree (64 live regs).
__global__ __launch_bounds__(1024, 4) void pml_main(
    const float* __restrict__ completed,
    const float* __restrict__ partial,
    float2* __restrict__ slots_out)
{
    const int tid  = threadIdx.x;
    const int lane = tid & 63;
    const int wave = tid >> 6;            // 0..15, owns 128 partials
    const int g    = lane >> 5;           // k-half
    const int lc   = lane & 31;           // A row (partial) / B col (point)
    const int batch = blockIdx.x >> 5;
    const int blkb  = blockIdx.x & (BLKSPB - 1);

    __shared__ uint4 sB[PTILES][2][32];         // 8 KB B-frags (points)
    __shared__ float smin[PTSBLK][WAVES + 1];   // 17 KB, pitch 17
    __shared__ float        rs[4];
    __shared__ unsigned int rc[4];

    const size_t cbase = ((size_t)batch * NCOMP + (size_t)blkb * PTSBLK) * 3;

    // ---- encode B-frags (block's 256 points) into LDS: tid<512 ----
    if (tid < 512) {
        const int tt = tid >> 6;              // tile 0..7
        const int idx = tid & 63;
        const int bg = idx >> 5;              // k-half 0/1
        const int pt = idx & 31;              // point col in tile
        const float* p = completed + cbase + 3 * (tt * 32 + pt);
        float x = p[0], y = p[1], z = p[2];
        uint4 o;
        if (bg == 0) {                        // k0..7
            unsigned int hx = bf16rne(x), hy = bf16rne(y), hz = bf16rne(z);
            unsigned int lx = bf16rne(x - bf16tof(hx));
            unsigned int ly = bf16rne(y - bf16tof(hy));
            unsigned int lz = bf16rne(z - bf16tof(hz));
            o.x = hx | (hy << 16);
            o.y = hz | (lx << 16);
            o.z = ly | (lz << 16);
            o.w = hx | (hy << 16);
        } else {                              // k8..15 = [chz, 1, 1, 0...]
            unsigned int hz = bf16rne(z);
            o.x = hz | (0x3F80u << 16);
            o.y = 0x3F80u;
            o.z = 0u;
            o.w = 0u;
        }
        sB[tt][bg][pt] = o;
    }

    // ---- encode this wave's 4 A-chunks (128 partials) in-register ----
    bf16x8 pa[ACHUNKS];
    {
        const size_t pbase = (size_t)batch * NPART + (size_t)wave * 128;
        #pragma unroll
        for (int i = 0; i < ACHUNKS; ++i) {
            const float* pp = partial + 3 * (pbase + i * 32 + lc);
            float px = pp[0], py = pp[1], pz = pp[2];
            frag_cast fc; fc.u = make_uint4(0u, 0u, 0u, 0u);
            if (g == 0) {                     // k0..7
                float qx = -2.0f * px, qy = -2.0f * py, qz = -2.0f * pz;
                unsigned int qhx = bf16rne(qx), qhy = bf16rne(qy), qhz = bf16rne(qz);
                unsigned int qlx = bf16rne(qx - bf16tof(qhx));
                unsigned int qly = bf16rne(qy - bf16tof(qhy));
                fc.u.x = qhx | (qhy << 16);
                fc.u.y = qhz | (qhx << 16);
                fc.u.z = qhy | (qhz << 16);
                fc.u.w = qlx | (qly << 16);
            } else {                          // k8..15 = [qlz, p2h, p2l, 0...]
                float qz = -2.0f * pz;
                float p2 = fmaf(px, px, fmaf(py, py, pz * pz));
                unsigned int qhz = bf16rne(qz);
                unsigned int qlz = bf16rne(qz - bf16tof(qhz));
                unsigned int p2h = bf16rne(p2);
                unsigned int p2l = bf16rne(p2 - bf16tof(p2h));
                fc.u.x = qlz | (p2h << 16);
                fc.u.y = p2l;
            }
            pa[i] = fc.v;
        }
    }

    __syncthreads();   // sB visible

    const f32x16 zero16 = {0.0f, 0.0f, 0.0f, 0.0f, 0.0f, 0.0f, 0.0f, 0.0f,
                           0.0f, 0.0f, 0.0f, 0.0f, 0.0f, 0.0f, 0.0f, 0.0f};

    // ---- sweep 8 point-tiles: min over partials folds in the accumulator ----
    for (int tile = 0; tile < PTILES; ++tile) {
        frag_cast fc; fc.u = sB[tile][g][lc];
        bf16x8 bf = fc.v;

        f32x16 acc = {FLTMAX, FLTMAX, FLTMAX, FLTMAX, FLTMAX, FLTMAX, FLTMAX, FLTMAX,
                      FLTMAX, FLTMAX, FLTMAX, FLTMAX, FLTMAX, FLTMAX, FLTMAX, FLTMAX};
        #pragma unroll
        for (int i = 0; i < ACHUNKS; ++i) {
            f32x16 d = __builtin_amdgcn_mfma_f32_32x32x16_bf16(pa[i], bf, zero16, 0, 0, 0);
            #pragma unroll
            for (int q = 0; q < 16; ++q)
                acc[q] = fminf(acc[q], d[q]);
        }
        // fold 16 regs (rows within lane-half), then the lane-half fold:
        // rows are bijective over 32 partials -> mapping-agnostic min
        float m0 = fminf(fminf(acc[0],  acc[1]),  fminf(acc[2],  acc[3]));
        float m1 = fminf(fminf(acc[4],  acc[5]),  fminf(acc[6],  acc[7]));
        float m2 = fminf(fminf(acc[8],  acc[9]),  fminf(acc[10], acc[11]));
        float m3 = fminf(fminf(acc[12], acc[13]), fminf(acc[14], acc[15]));
        float m = fminf(fminf(m0, m1), fminf(m2, m3));
        m = fminf(m, __int_as_float(__shfl_xor(__float_as_int(m), 32, 64)));
        if (lane < 32)
            smin[tile * 32 + lc][wave] = m;   // banks (17*(t*32+l))%32: bijective
    }
    __syncthreads();

    // ---- combine 16 wave-minima per point, +c2 (exact f32), mask, reduce ----
    float        v = 0.0f;
    unsigned int c = 0u;
    if (tid < PTSBLK) {
        float t = smin[tid][0];
        #pragma unroll
        for (int g2 = 1; g2 < WAVES; ++g2) t = fminf(t, smin[tid][g2]);
        const float* cp = completed + cbase + 3 * tid;
        float x = cp[0], y = cp[1], z = cp[2];
        float c2 = fmaf(x, x, fmaf(y, y, z * z));
        float m = fmaxf(c2 + t, 0.0f);
        if (m < THRESH) { v = m; c = 1u; }
        #pragma unroll
        for (int off = 32; off >= 1; off >>= 1) {
            v += __shfl_down(v, off, 64);
            c += __shfl_down(c, off, 64);
        }
        if ((tid & 63) == 0) { rs[tid >> 6] = v; rc[tid >> 6] = c; }
    }
    __syncthreads();
    if (tid == 0) {
        float        bs = 0.0f;
        unsigned int bc = 0u;
        #pragma unroll
        for (int w = 0; w < PTSBLK / 64; ++w) { bs += rs[w]; bc += rc[w]; }
        slots_out[blockIdx.x] = make_float2(bs, (float)bc);
    }
}

__global__ __launch_bounds__(256) void pml_fin(
    const float2* __restrict__ slots_in,
    float* __restrict__ out)
{
    const int tid = threadIdx.x;
    float2 sl = slots_in[tid];               // GRID == 256 == blockDim
    float s = sl.x, c = sl.y;
    #pragma unroll
    for (int off = 32; off >= 1; off >>= 1) {
        s += __shfl_down(s, off, 64);
        c += __shfl_down(c, off, 64);
    }
    __shared__ float ss[4], sc[4];
    if ((tid & 63) == 0) { ss[tid >> 6] = s; sc[tid >> 6] = c; }
    __syncthreads();
    if (tid == 0) {
        float s2 = ss[0] + ss[1] + ss[2] + ss[3];
        float c2 = sc[0] + sc[1] + sc[2] + sc[3];
        *out = (c2 > 0.0f) ? (s2 / (c2 + 1e-6f)) : 0.0f;   // WEIGHT = 1.0
    }
}

extern "C" void kernel_launch(void* const* d_in, const int* in_sizes, int n_in,
                              void* d_out, int out_size, void* d_ws, size_t ws_size,
                              hipStream_t stream) {
    const float* completed = (const float*)d_in[0];  // (8, 8192, 3) f32
    const float* partial   = (const float*)d_in[1];  // (8, 2048, 3) f32
    float* out = (float*)d_out;
    float2* slots = (float2*)d_ws;                   // 256 slots, all written
                                                     // before fin reads them:
                                                     // no memset node needed

    pml_main<<<dim3(GRID), dim3(1024), 0, stream>>>(completed, partial, slots);
    pml_fin<<<dim3(1), dim3(256), 0, stream>>>(slots, out);
}